// Round 11
// baseline (252.925 us; speedup 1.0000x reference)
//
#include <hip/hip_runtime.h>
#include <cstdint>
#include <cstddef>

constexpr int SEQ  = 2048;
constexpr int CH   = 1024;
constexpr int NH   = 16;
constexpr int HS   = 64;
constexpr int NB   = 2;
constexpr int HDIM = NH * HS; // 1024

typedef __bf16 bf16x8 __attribute__((ext_vector_type(8)));
typedef __bf16 bf16x4 __attribute__((ext_vector_type(4)));
typedef float  f32x4  __attribute__((ext_vector_type(4)));

__device__ __forceinline__ unsigned short f2bf(float f) {
  union { float f; unsigned u; } v; v.f = f;
  unsigned u = v.u;
  u += 0x7fffu + ((u >> 16) & 1u);   // RNE
  return (unsigned short)(u >> 16);
}
__device__ __forceinline__ float bf2f(unsigned short h) {
  union { unsigned u; float f; } v; v.u = ((unsigned)h) << 16;
  return v.f;
}
__device__ __forceinline__ float load_elem(const void* p, int flag, size_t idx) {
  if (flag) return ((const float*)p)[idx];
  return bf2f(((const unsigned short*)p)[idx]);
}
__device__ __forceinline__ void gl_lds16(const unsigned short* g, unsigned short* l) {
  __builtin_amdgcn_global_load_lds(
      (const __attribute__((address_space(1))) unsigned int*)g,
      (__attribute__((address_space(3))) unsigned int*)l, 16, 0, 0);
}

// ---- inline dtype detector (observed: inputs fp32; kept as insurance) ----
__device__ int detect_flag_block(const void* p, int n, int tid, int nthr) {
  __shared__ int det_good;
  if (tid == 0) det_good = 0;
  __syncthreads();
  const unsigned short* u = (const unsigned short*)p;
  int good = 0;
  for (int j = tid; j < n; j += nthr) {
    unsigned short v = u[2 * j];
    int e = (v >> 7) & 0xFF;
    if (v != 0 && e >= 90 && e <= 150) good++;
  }
  atomicAdd(&det_good, good);
  __syncthreads();
  return (det_good * 10 >= n * 7) ? 0 : 1;   // 0 = bf16, 1 = fp32
}

// ---- preprocessing: transpose Wq/Wk/Wv + transpose Wo (x-ingest moved to qkv) ----
__global__ __launch_bounds__(256) void prep(
    const void* __restrict__ wq, const void* __restrict__ wk,
    const void* __restrict__ wv, const void* __restrict__ wo,
    unsigned short* __restrict__ wall,   // [3][H][D][C]
    unsigned short* __restrict__ wot) {  // [C][HD]
  __shared__ unsigned short tile[32][36];   // stride 36 elems (72B), 8B-aligned cols
  int idx = blockIdx.x, tid = threadIdx.x;
  int row = tid >> 3, cg = (tid & 7) * 4;   // load mapping: 32 rows x 8 col-groups
  int col = tid >> 3, rg = (tid & 7) * 4;   // store mapping: 32 cols x 8 row-groups
  if (idx < 3072) {
    int which = idx >> 10, hh = (idx >> 6) & 15, sub = idx & 63;
    const void* src = (which == 0) ? wq : (which == 1) ? wk : wv;
    int f = detect_flag_block(src, 512, tid, 256);
    int c0 = (sub & 1) * 32;        // over HS (64)
    int r0 = (sub >> 1) * 32;       // over CH (1024)
    size_t boff = (size_t)hh * CH * HS;
    size_t si = boff + (size_t)(r0 + row) * HS + c0 + cg;
    ushort4 t4;
    if (f) {
      float4 v = *(const float4*)((const float*)src + si);
      t4.x = f2bf(v.x); t4.y = f2bf(v.y); t4.z = f2bf(v.z); t4.w = f2bf(v.w);
    } else {
      t4 = *(const ushort4*)((const unsigned short*)src + si);
    }
    *(ushort4*)&tile[row][cg] = t4;
    __syncthreads();
    unsigned short* d = wall + ((size_t)which * NH + hh) * HS * CH;
    ushort4 o;
    o.x = tile[rg + 0][col]; o.y = tile[rg + 1][col];
    o.z = tile[rg + 2][col]; o.w = tile[rg + 3][col];
    *(ushort4*)&d[(size_t)(c0 + col) * CH + r0 + rg] = o;
  } else {
    int sub = idx - 3072;
    int f = detect_flag_block(wo, 512, tid, 256);
    int c0 = (sub & 31) * 32;       // over CH (cols)
    int r0 = (sub >> 5) * 32;       // over HDIM (rows)
    size_t si = (size_t)(r0 + row) * CH + c0 + cg;
    ushort4 t4;
    if (f) {
      float4 v = *(const float4*)((const float*)wo + si);
      t4.x = f2bf(v.x); t4.y = f2bf(v.y); t4.z = f2bf(v.z); t4.w = f2bf(v.w);
    } else {
      t4 = *(const ushort4*)((const unsigned short*)wo + si);
    }
    *(ushort4*)&tile[row][cg] = t4;
    __syncthreads();
    ushort4 o;
    o.x = tile[rg + 0][col]; o.y = tile[rg + 1][col];
    o.z = tile[rg + 2][col]; o.w = tile[rg + 3][col];
    *(ushort4*)&wot[(size_t)(c0 + col) * HDIM + r0 + rg] = o;
  }
}

// ---- fused QKV GEMM: 128x192 tile, dbuf, 1 barrier/step.
// A (= x) is ingested DIRECTLY (fp32 or bf16 via runtime flag): T14-style
// reg-staging — issue A global loads before the MFMA phase, convert+ds_write
// after it. LDS layout identical to the gl_lds16 path (pre-swizzled global
// col gcol + linear-by-lane dest == chunk c holds global chunk c^(row&7)).
// B stays on async gl_lds16. grid (32,16)=512 blocks = 2/CU.
__global__ __launch_bounds__(256, 2) void qkv_gemm(
    const void* __restrict__ x,
    const unsigned short* __restrict__ wall,   // [3072][1024]
    unsigned short* __restrict__ qo,
    unsigned short* __restrict__ ko,
    unsigned short* __restrict__ vt) {
  __shared__ __attribute__((aligned(16))) unsigned short Al[2][128 * 64];
  __shared__ __attribute__((aligned(16))) unsigned short Bl[2][192 * 64];
  int tid = threadIdx.x, wave = tid >> 6, lane = tid & 63;
  int fx = detect_flag_block(x, 512, tid, 256);
  int mt = blockIdx.x, nt = blockIdx.y;
  const unsigned short* Bm = wall + (size_t)nt * 192 * CH;
  int quad = lane >> 4, l15 = lane & 15;
  int r8 = lane >> 3, c8 = lane & 7;
  int gcol = ((c8 ^ r8) << 3);
  int x7 = l15 & 7;
  int wm = (wave >> 1) * 64, wn = (wave & 1) * 96;
  f32x4 acc[4][6];
  #pragma unroll
  for (int i = 0; i < 4; i++)
    #pragma unroll
    for (int j = 0; j < 6; j++) acc[i][j] = (f32x4){0.f, 0.f, 0.f, 0.f};

  const float*          xf = (const float*)x          + (size_t)mt * 128 * CH;
  const unsigned short* xh = (const unsigned short*)x + (size_t)mt * 128 * CH;

  float4 fa[4][2]; uint4 ua[4];
  auto a_load = [&](int k0) {
    #pragma unroll
    for (int c = 0; c < 4; c++) {
      size_t src = (size_t)(wave * 32 + c * 8 + r8) * CH + k0 + gcol;
      if (fx) {
        fa[c][0] = *(const float4*)(xf + src);
        fa[c][1] = *(const float4*)(xf + src + 4);
      } else {
        ua[c] = *(const uint4*)(xh + src);
      }
    }
  };
  auto a_write = [&](int bb) {
    #pragma unroll
    for (int c = 0; c < 4; c++) {
      unsigned short* d = &Al[bb][(wave * 32 + c * 8) * 64 + lane * 8];
      if (fx) {
        uint4 o;
        o.x = (unsigned)f2bf(fa[c][0].x) | ((unsigned)f2bf(fa[c][0].y) << 16);
        o.y = (unsigned)f2bf(fa[c][0].z) | ((unsigned)f2bf(fa[c][0].w) << 16);
        o.z = (unsigned)f2bf(fa[c][1].x) | ((unsigned)f2bf(fa[c][1].y) << 16);
        o.w = (unsigned)f2bf(fa[c][1].z) | ((unsigned)f2bf(fa[c][1].w) << 16);
        *(uint4*)d = o;
      } else {
        *(uint4*)d = ua[c];
      }
    }
  };
  auto b_stage = [&](int bb, int k0) {
    #pragma unroll
    for (int c = 0; c < 6; c++) {
      int row = wave * 48 + c * 8 + r8;
      gl_lds16(&Bm[(size_t)row * CH + k0 + gcol], &Bl[bb][(wave * 48 + c * 8) * 64]);
    }
  };

  a_load(0); b_stage(0, 0);
  a_write(0);
  __syncthreads();
  for (int ks = 0; ks < 16; ks++) {
    int bb = ks & 1;
    if (ks < 15) { a_load((ks + 1) * 64); b_stage(bb ^ 1, (ks + 1) * 64); }  // issue-early
    #pragma unroll
    for (int h = 0; h < 2; h++) {
      int cq = ((quad + 4 * h) ^ x7) << 3;
      bf16x8 af[4], bfr[6];
      #pragma unroll
      for (int fm = 0; fm < 4; fm++)
        af[fm] = *reinterpret_cast<const bf16x8*>(&Al[bb][(wm + fm * 16 + l15) * 64 + cq]);
      #pragma unroll
      for (int fn = 0; fn < 6; fn++)
        bfr[fn] = *reinterpret_cast<const bf16x8*>(&Bl[bb][(wn + fn * 16 + l15) * 64 + cq]);
      __builtin_amdgcn_s_setprio(1);
      #pragma unroll
      for (int fm = 0; fm < 4; fm++)
        #pragma unroll
        for (int fn = 0; fn < 6; fn++)
          acc[fm][fn] = __builtin_amdgcn_mfma_f32_16x16x32_bf16(af[fm], bfr[fn], acc[fm][fn], 0, 0, 0);
      __builtin_amdgcn_s_setprio(0);
    }
    if (ks < 15) a_write(bb ^ 1);   // cvt + LDS write after MFMA: load latency hidden
    __syncthreads();
  }

  // epilogue: per-fragment q/k/v segment selection (192-col tile straddles
  // the 1024-col boundaries; seg is lane-uniform per fragment since
  // boundaries are 16-aligned)
  #pragma unroll
  for (int fn = 0; fn < 6; fn++) {
    int c0 = nt * 192 + wn + fn * 16;
    int seg = c0 >> 10;
    int hd = (c0 & 1023) + l15;
    int h = hd >> 6, d = hd & 63;
    if (seg < 2) {
      unsigned short* dst = (seg == 0) ? qo : ko;
      float s = (seg == 0) ? 0.18033688011112042f : 1.0f;  // 0.125*log2(e) folded into q
      #pragma unroll
      for (int fm = 0; fm < 4; fm++) {
        int m = mt * 128 + wm + fm * 16 + quad * 4;
        int b = m >> 11, s0 = m & 2047;
        #pragma unroll
        for (int r = 0; r < 4; r++)
          dst[(((size_t)b * NH + h) * SEQ + s0 + r) * HS + d] = f2bf(acc[fm][fn][r] * s);
      }
    } else { // v transposed: vt[b][h][d][s]
      #pragma unroll
      for (int fm = 0; fm < 4; fm++) {
        int m = mt * 128 + wm + fm * 16 + quad * 4;
        int b = m >> 11, s0 = m & 2047;
        ushort4 pk;
        pk.x = f2bf(acc[fm][fn][0]); pk.y = f2bf(acc[fm][fn][1]);
        pk.z = f2bf(acc[fm][fn][2]); pk.w = f2bf(acc[fm][fn][3]);
        *(ushort4*)&vt[(((size_t)b * NH + h) * HS + d) * SEQ + s0] = pk;
      }
    }
  }
}

// ---- softmax + P^T pack for one fragment (S^T C-layout in regs) ----
template <bool MASKED>
__device__ __forceinline__ void soft_pack(const f32x4* s, f32x4& ls,
                                          unsigned short* ptRow, int quad, int tmb) {
  #pragma unroll
  for (int tb = 0; tb < 4; tb++) {
    f32x4 pv;
    #pragma unroll
    for (int r = 0; r < 4; r++) {
      float p = __builtin_amdgcn_exp2f(s[tb][r]);
      if (MASKED) { if (tmb + tb * 16 + quad * 4 + r > 0) p = 0.f; }
      pv[r] = p;
    }
    ls += pv;
    bf16x4 pk;
    pk.x = (__bf16)pv[0]; pk.y = (__bf16)pv[1];
    pk.z = (__bf16)pv[2]; pk.w = (__bf16)pv[3];
    *(bf16x4*)&ptRow[tb * 16 + quad * 4] = pk;
  }
}

// ---- one pipeline step: read P(t-1) from Pt FIRST (write completed under the
// previous barrier -> no write->read turnaround stall), then QK(t) + PV(t-1)
// as interleaved MFMA streams, then softmax(t) -> Pt.
// QKM: 0 = both sides free; 1 = side0 masked + side1 free;
//      2 = side1 only, free; 3 = side1 only, masked.
// PV0: side0 PV active. PVV: any PV this step (false only at t=0).
// K/V tiles XOR-swizzled: 16B chunk c of row r at chunk c^(r&7).
template <int QKM, bool PV0, bool PVV>
__device__ __forceinline__ void attn_step(
    const unsigned short (&Kb)[64][64], const unsigned short (&Vp)[64][64],
    unsigned short* p0row, unsigned short* p1row,
    const bf16x8 (&qf)[2][2], f32x4 (&lsum)[2], f32x4 (&accO)[2][4],
    int quad, int l15, int tmb) {
  constexpr bool C0 = (QKM <= 1);
  constexpr bool M0 = (QKM == 1);
  constexpr bool M1 = (QKM == 3);
  int x7 = l15 & 7;
  // read P(t-1) fragments (issued early; latency hides under K reads + MFMA)
  bf16x8 pb0[2], pb1[2];
  if (PVV) {
    #pragma unroll
    for (int tp = 0; tp < 2; tp++) {
      if (PV0) pb0[tp] = *reinterpret_cast<const bf16x8*>(&p0row[tp * 32 + quad * 8]);
      pb1[tp] = *reinterpret_cast<const bf16x8*>(&p1row[tp * 32 + quad * 8]);
    }
  }
  f32x4 s0[4], s1[4];
  #pragma unroll
  for (int tb = 0; tb < 4; tb++) { s0[tb] = (f32x4){0,0,0,0}; s1[tb] = (f32x4){0,0,0,0}; }
  __builtin_amdgcn_s_setprio(1);
  // QK(t)
  #pragma unroll
  for (int tb = 0; tb < 4; tb++)
    #pragma unroll
    for (int hh = 0; hh < 2; hh++) {
      bf16x8 kf = *reinterpret_cast<const bf16x8*>(
          &Kb[tb * 16 + l15][((hh * 4 + quad) ^ x7) << 3]);
      if (C0) s0[tb] = __builtin_amdgcn_mfma_f32_16x16x32_bf16(kf, qf[0][hh], s0[tb], 0, 0, 0);
      s1[tb] = __builtin_amdgcn_mfma_f32_16x16x32_bf16(kf, qf[1][hh], s1[tb], 0, 0, 0);
    }
  // PV(t-1): independent MFMA stream; softmax(t) VALU overlaps its completion.
  if (PVV) {
    #pragma unroll
    for (int db = 0; db < 4; db++)
      #pragma unroll
      for (int tp = 0; tp < 2; tp++) {
        bf16x8 vf = *reinterpret_cast<const bf16x8*>(
            &Vp[db * 16 + l15][((tp * 4 + quad) ^ x7) << 3]);
        if (PV0) accO[0][db] = __builtin_amdgcn_mfma_f32_16x16x32_bf16(vf, pb0[tp], accO[0][db], 0, 0, 0);
        accO[1][db] = __builtin_amdgcn_mfma_f32_16x16x32_bf16(vf, pb1[tp], accO[1][db], 0, 0, 0);
      }
  }
  __builtin_amdgcn_s_setprio(0);
  // softmax(t) + pack into Pt (consumed at step t+1 / epilogue)
  if (C0) soft_pack<M0>(s0, lsum[0], p0row, quad, tmb);
  soft_pack<M1>(s1, lsum[1], p1row, quad, tmb);
}

// ---- flash attention, paired-supertile balanced blocks + deferred-PV pipeline.
// XCD-grouped remap (512 blocks, grid (16,32), n = x + 16*y):
//   g = n&7 (XCD), idx = n>>3, p = idx&15, bh = g*4 + (idx>>4)  [idx>>4 in 0..3]
// -> bijective onto (p in [0,16), bh in [0,32)); all 16 p-blocks of one bh land
// on XCD g; 4 bh per XCD = 2MB K/V inside one 4MB XCD L2.
// (R10's p-complement "CU-pair balance" variant measured +3.8us — reverted.)
// block handles q-supertiles st0=p and st1=31-p (constant 33 tile-sides).
// Triple-buffered K/V LDS: iter t reads K[t%3] (QK) and V[(t-1)%3] (deferred PV),
// stages t+1 into (t+1)%3. One barrier per iter; PV off the critical chain.
// g2r staging uses pointer increments (constant stride/step).
__global__ __launch_bounds__(256) void attn_k(
    const unsigned short* __restrict__ q,
    const unsigned short* __restrict__ k,
    const unsigned short* __restrict__ vt,
    unsigned short* __restrict__ y) {
  __shared__ __attribute__((aligned(16))) unsigned short Kl[3][64][64];
  __shared__ __attribute__((aligned(16))) unsigned short Vl[3][64][64];
  __shared__ __attribute__((aligned(16))) unsigned short Pt[4][16][152];

  // bijective XCD-locality remap (512 blocks)
  int n = blockIdx.x + 16 * blockIdx.y;
  int g = n & 7, idx = n >> 3;
  int p = idx & 15;                   // 0..15
  int bh = g * 4 + (idx >> 4);        // idx>>4 in [0,4) -> bh in [0,32)
  int st0 = p, st1 = 31 - p;          // st0 < 16 <= st1
  int b = bh >> 4, h = bh & 15;
  const unsigned short* Q0 = q + ((size_t)bh * SEQ + st0 * 64) * HS;
  const unsigned short* Q1 = q + ((size_t)bh * SEQ + st1 * 64) * HS;
  const unsigned short* K  = k  + (size_t)bh * SEQ * HS;
  const unsigned short* V  = vt + (size_t)bh * HS * SEQ;   // [d][s]
  int tid = threadIdx.x, wave = tid >> 6, lane = tid & 63;
  int quad = lane >> 4, l15 = lane & 15;
  int lr = tid >> 3, lc = (tid & 7) * 8;
  int sc = (((tid & 7) ^ (lr & 7)) << 3);        // swizzled LDS chunk offset

  bf16x8 qf[2][2];
  #pragma unroll
  for (int hh = 0; hh < 2; hh++) {
    qf[0][hh] = *reinterpret_cast<const bf16x8*>(
        &Q0[(size_t)(wave * 16 + l15) * HS + hh * 32 + quad * 8]);
    qf[1][hh] = *reinterpret_cast<const bf16x8*>(
        &Q1[(size_t)(wave * 16 + l15) * HS + hh * 32 + quad * 8]);
  }

  f32x4 lsum[2] = {(f32x4){0,0,0,0}, (f32x4){0,0,0,0}};
  f32x4 accO[2][4];
  #pragma unroll
  for (int f = 0; f < 2; f++)
    #pragma unroll
    for (int i = 0; i < 4; i++) accO[f][i] = (f32x4){0.f, 0.f, 0.f, 0.f};

  unsigned short* p0row = &Pt[wave][l15][0];
  unsigned short* p1row = &Pt[wave][l15][64];
  int tmb = -(wave * 16 + l15);

  // staging pointers, advanced by constant stride per kv-tile
  const unsigned short* pK0 = K + (size_t)lr * HS + lc;
  const unsigned short* pK1 = pK0 + (size_t)32 * HS;
  const unsigned short* pV0 = V + (size_t)lr * SEQ + lc;
  const unsigned short* pV1 = pV0 + (size_t)32 * SEQ;
  uint4 kr0, kr1, vr0, vr1;
  auto g2r = [&]() {
    kr0 = *(const uint4*)pK0; kr1 = *(const uint4*)pK1;
    vr0 = *(const uint4*)pV0; vr1 = *(const uint4*)pV1;
    pK0 += 64 * HS; pK1 += 64 * HS; pV0 += 64; pV1 += 64;
  };
  auto r2l = [&](int nb) {
    *(uint4*)&Kl[nb][lr][sc] = kr0; *(uint4*)&Kl[nb][lr + 32][sc] = kr1;
    *(uint4*)&Vl[nb][lr][sc] = vr0; *(uint4*)&Vl[nb][lr + 32][sc] = vr1;
  };

  g2r(); r2l(0);
  __syncthreads();

  // ---- t = 0: QK/SM only (no PV yet)
  {
    if (st1 > 0) g2r();
    if (st0 == 0)
      attn_step<1, false, false>(Kl[0], Vl[2], p0row, p1row, qf, lsum, accO, quad, l15, tmb);
    else
      attn_step<0, false, false>(Kl[0], Vl[2], p0row, p1row, qf, lsum, accO, quad, l15, tmb);
    if (st1 > 0) r2l(1);
    __syncthreads();
  }
  // ---- t = 1 .. st0-1 : both sides QK free, PV both
  for (int t = 1; t < st0; t++) {
    g2r();
    attn_step<0, true, true>(Kl[t % 3], Vl[(t + 2) % 3], p0row, p1row, qf, lsum, accO, quad, l15, tmb);
    r2l((t + 1) % 3);
    __syncthreads();
  }
  // ---- t = st0 (if >=1): side0 masked QK, PV both
  if (st0 >= 1) {
    int t = st0;
    g2r();
    attn_step<1, true, true>(Kl[t % 3], Vl[(t + 2) % 3], p0row, p1row, qf, lsum, accO, quad, l15, tmb);
    r2l((t + 1) % 3);
    __syncthreads();
  }
  // ---- t = st0+1: side1-only QK (masked iff == st1), side0's LAST PV
  {
    int t = st0 + 1;
    bool more = (t < st1);
    if (more) g2r();
    if (t == st1)
      attn_step<3, true, true>(Kl[t % 3], Vl[(t + 2) % 3], p0row, p1row, qf, lsum, accO, quad, l15, tmb);
    else
      attn_step<2, true, true>(Kl[t % 3], Vl[(t + 2) % 3], p0row, p1row, qf, lsum, accO, quad, l15, tmb);
    if (more) r2l((t + 1) % 3);
    __syncthreads();
  }
  // ---- t = st0+2 .. st1-1 : side1 only
  for (int t = st0 + 2; t < st1; t++) {
    g2r();
    attn_step<2, false, true>(Kl[t % 3], Vl[(t + 2) % 3], p0row, p1row, qf, lsum, accO, quad, l15, tmb);
    r2l((t + 1) % 3);
    __syncthreads();
  }
  // ---- t = st1 (if not already done above): masked side1 QK, PV side1
  if (st1 >= st0 + 2) {
    int t = st1;
    attn_step<3, false, true>(Kl[t % 3], Vl[(t + 2) % 3], p0row, p1row, qf, lsum, accO, quad, l15, tmb);
  }
  // ---- epilogue PV for side1's last tile: read P(st1) back, multiply V(st1)
  {
    const unsigned short (&Vb)[64][64] = Vl[st1 % 3];
    int x7 = l15 & 7;
    bf16x8 pb1[2];
    #pragma unroll
    for (int tp = 0; tp < 2; tp++)
      pb1[tp] = *reinterpret_cast<const bf16x8*>(&p1row[tp * 32 + quad * 8]);
    #pragma unroll
    for (int db = 0; db < 4; db++)
      #pragma unroll
      for (int tp = 0; tp < 2; tp++) {
        bf16x8 vf = *reinterpret_cast<const bf16x8*>(
            &Vb[db * 16 + l15][((tp * 4 + quad) ^ x7) << 3]);
        accO[1][db] = __builtin_amdgcn_mfma_f32_16x16x32_bf16(vf, pb1[tp], accO[1][db], 0, 0, 0);
      }
  }

  // epilogue: horizontal lsum, reduce over quads, normalize, write both sides
  #pragma unroll
  for (int f = 0; f < 2; f++) {
    float rs = (lsum[f][0] + lsum[f][1]) + (lsum[f][2] + lsum[f][3]);
    rs += __shfl_xor(rs, 16); rs += __shfl_xor(rs, 32);
    float inv = 1.0f / fmaxf(rs, 1e-30f);
    int srow = (f == 0 ? st0 : st1) * 64 + wave * 16 + l15;
    #pragma unroll
    for (int db = 0; db < 4; db++) {
      ushort4 pk;
      pk.x = f2bf(accO[f][db][0] * inv); pk.y = f2bf(accO[f][db][1] * inv);
      pk.z = f2bf(accO[f][db][2] * inv); pk.w = f2bf(accO[f][db][3] * inv);
      *(ushort4*)&y[((size_t)b * SEQ + srow) * HDIM + h * 64 + db * 16 + quad * 4] = pk;
    }
  }
}

// ---- output projection, 128x64 tile, dbuf issue-early, 1 barrier/step ----
__global__ __launch_bounds__(256) void out_gemm(
    const unsigned short* __restrict__ y,
    const unsigned short* __restrict__ wot,
    const void* __restrict__ bo,
    float* __restrict__ out) {
  __shared__ __attribute__((aligned(16))) unsigned short Al[2][128 * 64];
  __shared__ __attribute__((aligned(16))) unsigned short Bl[2][64 * 64];
  int tid = threadIdx.x;
  int fbo = detect_flag_block(bo, 512, tid, 256);
  int mt = blockIdx.x, nt = blockIdx.y;
  const unsigned short* A  = y   + (size_t)mt * 128 * HDIM;
  const unsigned short* Bm = wot + (size_t)nt * 64 * HDIM;
  int wave = tid >> 6, lane = tid & 63;
  int quad = lane >> 4, l15 = lane & 15;
  int r8 = lane >> 3, c8 = lane & 7;
  int gcol = ((c8 ^ r8) << 3);
  int x7 = l15 & 7;
  int wm = (wave >> 1) * 64, wn = (wave & 1) * 32;
  f32x4 acc[4][2];
  #pragma unroll
  for (int i = 0; i < 4; i++)
    #pragma unroll
    for (int j = 0; j < 2; j++) acc[i][j] = (f32x4){0.f, 0.f, 0.f, 0.f};

  auto stage = [&](int bb, int k0) {
    #pragma unroll
    for (int c = 0; c < 4; c++) {
      int row = wave * 32 + c * 8 + r8;
      gl_lds16(&A[(size_t)row * HDIM + k0 + gcol], &Al[bb][(wave * 32 + c * 8) * 64]);
    }
    #pragma unroll
    for (int c = 0; c < 2; c++) {
      int row = wave * 16 + c * 8 + r8;
      gl_lds16(&Bm[(size_t)row * HDIM + k0 + gcol], &Bl[bb][(wave * 16 + c * 8) * 64]);
    }
  };

  stage(0, 0);
  __syncthreads();
  for (int ks = 0; ks < 16; ks++) {
    int bb = ks & 1;
    if (ks < 15) stage(bb ^ 1, (ks + 1) * 64);   // issue-early
    #pragma unroll
    for (int h = 0; h < 2; h++) {
      int cq = ((quad + 4 * h) ^ x7) << 3;
      bf16x8 af[4], bfr[2];
      #pragma unroll
      for (int fm = 0; fm < 4; fm++)
        af[fm] = *reinterpret_cast<const bf16x8*>(&Al[bb][(wm + fm * 16 + l15) * 64 + cq]);
      #pragma unroll
      for (int fn = 0; fn < 2; fn++)
        bfr[fn] = *reinterpret_cast<const bf16x8*>(&Bl[bb][(wn + fn * 16 + l15) * 64 + cq]);
      __builtin_amdgcn_s_setprio(1);
      #pragma unroll
      for (int fm = 0; fm < 4; fm++)
        #pragma unroll
        for (int fn = 0; fn < 2; fn++)
          acc[fm][fn] = __builtin_amdgcn_mfma_f32_16x16x32_bf16(af[fm], bfr[fn], acc[fm][fn], 0, 0, 0);
      __builtin_amdgcn_s_setprio(0);
    }
    __syncthreads();
  }

  #pragma unroll
  for (int fn = 0; fn < 2; fn++) {
    int n = nt * 64 + wn + fn * 16 + l15;
    float bias = load_elem(bo, fbo, n);
    #pragma unroll
    for (int fm = 0; fm < 4; fm++) {
      int m = mt * 128 + wm + fm * 16 + quad * 4;
      #pragma unroll
      for (int r = 0; r < 4; r++)
        out[(size_t)(m + r) * CH + n] = acc[fm][fn][r] + bias;
    }
  }
}

extern "C" void kernel_launch(void* const* d_in, const int* in_sizes, int n_in,
                              void* d_out, int out_size, void* d_ws, size_t ws_size,
                              hipStream_t stream) {
  const void* x  = d_in[0];
  const void* Wq = d_in[1];
  const void* Wk = d_in[2];
  const void* Wv = d_in[3];
  const void* Wo = d_in[4];
  const void* bo = d_in[5];
  float* out = (float*)d_out;

  char* ws = (char*)d_ws;
  const size_t MB = 1024 * 1024;
  unsigned short* qb   = (unsigned short*)(ws + 0);        // [B,H,S,D]  8MB (pre-scaled)
  unsigned short* kb   = (unsigned short*)(ws + 8  * MB);  // [B,H,S,D]  8MB
  unsigned short* vtb  = (unsigned short*)(ws + 16 * MB);  // [B,H,D,S]  8MB
  unsigned short* yb   = (unsigned short*)(ws + 24 * MB);  // [B,S,HD]   8MB
  unsigned short* wall = (unsigned short*)(ws + 32 * MB);  // [3][H,D,C] 6MB contiguous
  unsigned short* wot  = (unsigned short*)(ws + 38 * MB);  // [C,HD]     2MB

  prep<<<4096, 256, 0, stream>>>(Wq, Wk, Wv, Wo, wall, wot);
  qkv_gemm<<<dim3(NB * SEQ / 128, 3 * HDIM / 192), 256, 0, stream>>>(x, wall, qb, kb, vtb);
  attn_k<<<dim3(16, NB * NH), 256, 0, stream>>>(qb, kb, vtb, yb);
  out_gemm<<<dim3(NB * SEQ / 128, CH / 64), 256, 0, stream>>>(yb, wot, bo, out);
}

// Round 12
// 168.568 us; speedup vs baseline: 1.5004x; 1.5004x over previous
//
#include <hip/hip_runtime.h>
#include <cstdint>
#include <cstddef>

constexpr int SEQ  = 2048;
constexpr int CH   = 1024;
constexpr int NH   = 16;
constexpr int HS   = 64;
constexpr int NB   = 2;
constexpr int HDIM = NH * HS; // 1024

typedef __bf16 bf16x8 __attribute__((ext_vector_type(8)));
typedef __bf16 bf16x4 __attribute__((ext_vector_type(4)));
typedef float  f32x4  __attribute__((ext_vector_type(4)));

__device__ __forceinline__ unsigned short f2bf(float f) {
  union { float f; unsigned u; } v; v.f = f;
  unsigned u = v.u;
  u += 0x7fffu + ((u >> 16) & 1u);   // RNE
  return (unsigned short)(u >> 16);
}
__device__ __forceinline__ float bf2f(unsigned short h) {
  union { unsigned u; float f; } v; v.u = ((unsigned)h) << 16;
  return v.f;
}
__device__ __forceinline__ float load_elem(const void* p, int flag, size_t idx) {
  if (flag) return ((const float*)p)[idx];
  return bf2f(((const unsigned short*)p)[idx]);
}
__device__ __forceinline__ void gl_lds16(const unsigned short* g, unsigned short* l) {
  __builtin_amdgcn_global_load_lds(
      (const __attribute__((address_space(1))) unsigned int*)g,
      (__attribute__((address_space(3))) unsigned int*)l, 16, 0, 0);
}

// ---- inline dtype detector (observed: inputs fp32; kept as insurance) ----
__device__ int detect_flag_block(const void* p, int n, int tid, int nthr) {
  __shared__ int det_good;
  if (tid == 0) det_good = 0;
  __syncthreads();
  const unsigned short* u = (const unsigned short*)p;
  int good = 0;
  for (int j = tid; j < n; j += nthr) {
    unsigned short v = u[2 * j];
    int e = (v >> 7) & 0xFF;
    if (v != 0 && e >= 90 && e <= 150) good++;
  }
  atomicAdd(&det_good, good);
  __syncthreads();
  return (det_good * 10 >= n * 7) ? 0 : 1;   // 0 = bf16, 1 = fp32
}

// ---- fused preprocessing: ingest x + transpose Wq/Wk/Wv + transpose Wo ----
// transposes vectorized: float4 global loads -> LDS tile -> ushort4 stores.
__global__ __launch_bounds__(256) void prep(
    const void* __restrict__ x,  const void* __restrict__ wq,
    const void* __restrict__ wk, const void* __restrict__ wv,
    const void* __restrict__ wo,
    unsigned short* __restrict__ xb,
    unsigned short* __restrict__ wall,   // [3][H][D][C]
    unsigned short* __restrict__ wot) {  // [C][HD]
  __shared__ unsigned short tile[32][36];   // stride 36 elems (72B), 8B-aligned cols
  int idx = blockIdx.x, tid = threadIdx.x;
  int row = tid >> 3, cg = (tid & 7) * 4;   // load mapping: 32 rows x 8 col-groups
  int col = tid >> 3, rg = (tid & 7) * 4;   // store mapping: 32 cols x 8 row-groups
  if (idx < 1024) {
    int f = detect_flag_block(x, 512, tid, 256);
    size_t n4 = (size_t)NB * SEQ * CH / 4;
    for (size_t i = (size_t)idx * 256 + tid; i < n4; i += (size_t)1024 * 256) {
      ushort4 o;
      if (f) {
        float4 v = ((const float4*)x)[i];
        o.x = f2bf(v.x); o.y = f2bf(v.y); o.z = f2bf(v.z); o.w = f2bf(v.w);
      } else {
        o = ((const ushort4*)x)[i];
      }
      ((ushort4*)xb)[i] = o;
    }
  } else if (idx < 4096) {
    int j = idx - 1024;
    int which = j >> 10, hh = (j >> 6) & 15, sub = j & 63;
    const void* src = (which == 0) ? wq : (which == 1) ? wk : wv;
    int f = detect_flag_block(src, 512, tid, 256);
    int c0 = (sub & 1) * 32;        // over HS (64)
    int r0 = (sub >> 1) * 32;       // over CH (1024)
    size_t boff = (size_t)hh * CH * HS;
    size_t si = boff + (size_t)(r0 + row) * HS + c0 + cg;
    ushort4 t4;
    if (f) {
      float4 v = *(const float4*)((const float*)src + si);
      t4.x = f2bf(v.x); t4.y = f2bf(v.y); t4.z = f2bf(v.z); t4.w = f2bf(v.w);
    } else {
      t4 = *(const ushort4*)((const unsigned short*)src + si);
    }
    *(ushort4*)&tile[row][cg] = t4;
    __syncthreads();
    unsigned short* d = wall + ((size_t)which * NH + hh) * HS * CH;
    ushort4 o;
    o.x = tile[rg + 0][col]; o.y = tile[rg + 1][col];
    o.z = tile[rg + 2][col]; o.w = tile[rg + 3][col];
    *(ushort4*)&d[(size_t)(c0 + col) * CH + r0 + rg] = o;
  } else {
    int sub = idx - 4096;
    int f = detect_flag_block(wo, 512, tid, 256);
    int c0 = (sub & 31) * 32;       // over CH (cols)
    int r0 = (sub >> 5) * 32;       // over HDIM (rows)
    size_t si = (size_t)(r0 + row) * CH + c0 + cg;
    ushort4 t4;
    if (f) {
      float4 v = *(const float4*)((const float*)wo + si);
      t4.x = f2bf(v.x); t4.y = f2bf(v.y); t4.z = f2bf(v.z); t4.w = f2bf(v.w);
    } else {
      t4 = *(const ushort4*)((const unsigned short*)wo + si);
    }
    *(ushort4*)&tile[row][cg] = t4;
    __syncthreads();
    ushort4 o;
    o.x = tile[rg + 0][col]; o.y = tile[rg + 1][col];
    o.z = tile[rg + 2][col]; o.w = tile[rg + 3][col];
    *(ushort4*)&wot[(size_t)(c0 + col) * HDIM + r0 + rg] = o;
  }
}

// ---- fused QKV GEMM: 128x192 tile, dbuf issue-early staging, 1 barrier/step.
// grid (32,16)=512 blocks = exactly 2/CU (one full round); LDS 80KB -> 2 resident.
__global__ __launch_bounds__(256, 2) void qkv_gemm(
    const unsigned short* __restrict__ xb,
    const unsigned short* __restrict__ wall,   // [3072][1024]
    unsigned short* __restrict__ qo,
    unsigned short* __restrict__ ko,
    unsigned short* __restrict__ vt) {
  __shared__ __attribute__((aligned(16))) unsigned short Al[2][128 * 64];
  __shared__ __attribute__((aligned(16))) unsigned short Bl[2][192 * 64];
  int mt = blockIdx.x, nt = blockIdx.y;
  const unsigned short* A  = xb   + (size_t)mt * 128 * CH;
  const unsigned short* Bm = wall + (size_t)nt * 192 * CH;
  int tid = threadIdx.x, wave = tid >> 6, lane = tid & 63;
  int quad = lane >> 4, l15 = lane & 15;
  int r8 = lane >> 3, c8 = lane & 7;
  int gcol = ((c8 ^ r8) << 3);
  int x7 = l15 & 7;
  int wm = (wave >> 1) * 64, wn = (wave & 1) * 96;
  f32x4 acc[4][6];
  #pragma unroll
  for (int i = 0; i < 4; i++)
    #pragma unroll
    for (int j = 0; j < 6; j++) acc[i][j] = (f32x4){0.f, 0.f, 0.f, 0.f};

  auto stage = [&](int bb, int k0) {
    #pragma unroll
    for (int c = 0; c < 4; c++) {
      int row = wave * 32 + c * 8 + r8;
      gl_lds16(&A[(size_t)row * CH + k0 + gcol], &Al[bb][(wave * 32 + c * 8) * 64]);
    }
    #pragma unroll
    for (int c = 0; c < 6; c++) {
      int row = wave * 48 + c * 8 + r8;
      gl_lds16(&Bm[(size_t)row * CH + k0 + gcol], &Bl[bb][(wave * 48 + c * 8) * 64]);
    }
  };

  stage(0, 0);
  __syncthreads();
  for (int ks = 0; ks < 16; ks++) {
    int bb = ks & 1;
    if (ks < 15) stage(bb ^ 1, (ks + 1) * 64);   // issue-early: latency hides under MFMA
    #pragma unroll
    for (int h = 0; h < 2; h++) {
      int cq = ((quad + 4 * h) ^ x7) << 3;
      bf16x8 af[4], bfr[6];
      #pragma unroll
      for (int fm = 0; fm < 4; fm++)
        af[fm] = *reinterpret_cast<const bf16x8*>(&Al[bb][(wm + fm * 16 + l15) * 64 + cq]);
      #pragma unroll
      for (int fn = 0; fn < 6; fn++)
        bfr[fn] = *reinterpret_cast<const bf16x8*>(&Bl[bb][(wn + fn * 16 + l15) * 64 + cq]);
      __builtin_amdgcn_s_setprio(1);
      #pragma unroll
      for (int fm = 0; fm < 4; fm++)
        #pragma unroll
        for (int fn = 0; fn < 6; fn++)
          acc[fm][fn] = __builtin_amdgcn_mfma_f32_16x16x32_bf16(af[fm], bfr[fn], acc[fm][fn], 0, 0, 0);
      __builtin_amdgcn_s_setprio(0);
    }
    __syncthreads();
  }

  // epilogue: per-fragment q/k/v segment selection (192-col tile straddles
  // the 1024-col boundaries; seg is lane-uniform per fragment since
  // boundaries are 16-aligned)
  #pragma unroll
  for (int fn = 0; fn < 6; fn++) {
    int c0 = nt * 192 + wn + fn * 16;
    int seg = c0 >> 10;
    int hd = (c0 & 1023) + l15;
    int h = hd >> 6, d = hd & 63;
    if (seg < 2) {
      unsigned short* dst = (seg == 0) ? qo : ko;
      float s = (seg == 0) ? 0.18033688011112042f : 1.0f;  // 0.125*log2(e) folded into q
      #pragma unroll
      for (int fm = 0; fm < 4; fm++) {
        int m = mt * 128 + wm + fm * 16 + quad * 4;
        int b = m >> 11, s0 = m & 2047;
        #pragma unroll
        for (int r = 0; r < 4; r++)
          dst[(((size_t)b * NH + h) * SEQ + s0 + r) * HS + d] = f2bf(acc[fm][fn][r] * s);
      }
    } else { // v transposed: vt[b][h][d][s]
      #pragma unroll
      for (int fm = 0; fm < 4; fm++) {
        int m = mt * 128 + wm + fm * 16 + quad * 4;
        int b = m >> 11, s0 = m & 2047;
        ushort4 pk;
        pk.x = f2bf(acc[fm][fn][0]); pk.y = f2bf(acc[fm][fn][1]);
        pk.z = f2bf(acc[fm][fn][2]); pk.w = f2bf(acc[fm][fn][3]);
        *(ushort4*)&vt[(((size_t)b * NH + h) * HS + d) * SEQ + s0] = pk;
      }
    }
  }
}

// ---- softmax + P^T pack for one fragment (S^T C-layout in regs) ----
template <bool MASKED>
__device__ __forceinline__ void soft_pack(const f32x4* s, f32x4& ls,
                                          unsigned short* ptRow, int quad, int tmb) {
  #pragma unroll
  for (int tb = 0; tb < 4; tb++) {
    f32x4 pv;
    #pragma unroll
    for (int r = 0; r < 4; r++) {
      float p = __builtin_amdgcn_exp2f(s[tb][r]);
      if (MASKED) { if (tmb + tb * 16 + quad * 4 + r > 0) p = 0.f; }
      pv[r] = p;
    }
    ls += pv;
    bf16x4 pk;
    pk.x = (__bf16)pv[0]; pk.y = (__bf16)pv[1];
    pk.z = (__bf16)pv[2]; pk.w = (__bf16)pv[3];
    *(bf16x4*)&ptRow[tb * 16 + quad * 4] = pk;
  }
}

// ---- one pipeline step: read P(t-1) from Pt FIRST (write completed under the
// previous barrier -> no write->read turnaround stall), then QK(t) + PV(t-1)
// as interleaved MFMA streams, then softmax(t) -> Pt.
// QKM: 0 = both sides free; 1 = side0 masked + side1 free;
//      2 = side1 only, free; 3 = side1 only, masked.
// PV0: side0 PV active. PVV: any PV this step (false only at t=0).
// K/V tiles XOR-swizzled: 16B chunk c of row r at chunk c^(r&7).
template <int QKM, bool PV0, bool PVV>
__device__ __forceinline__ void attn_step(
    const unsigned short (&Kb)[64][64], const unsigned short (&Vp)[64][64],
    unsigned short* p0row, unsigned short* p1row,
    const bf16x8 (&qf)[2][2], f32x4 (&lsum)[2], f32x4 (&accO)[2][4],
    int quad, int l15, int tmb) {
  constexpr bool C0 = (QKM <= 1);
  constexpr bool M0 = (QKM == 1);
  constexpr bool M1 = (QKM == 3);
  int x7 = l15 & 7;
  // read P(t-1) fragments (issued early; latency hides under K reads + MFMA)
  bf16x8 pb0[2], pb1[2];
  if (PVV) {
    #pragma unroll
    for (int tp = 0; tp < 2; tp++) {
      if (PV0) pb0[tp] = *reinterpret_cast<const bf16x8*>(&p0row[tp * 32 + quad * 8]);
      pb1[tp] = *reinterpret_cast<const bf16x8*>(&p1row[tp * 32 + quad * 8]);
    }
  }
  f32x4 s0[4], s1[4];
  #pragma unroll
  for (int tb = 0; tb < 4; tb++) { s0[tb] = (f32x4){0,0,0,0}; s1[tb] = (f32x4){0,0,0,0}; }
  __builtin_amdgcn_s_setprio(1);
  // QK(t)
  #pragma unroll
  for (int tb = 0; tb < 4; tb++)
    #pragma unroll
    for (int hh = 0; hh < 2; hh++) {
      bf16x8 kf = *reinterpret_cast<const bf16x8*>(
          &Kb[tb * 16 + l15][((hh * 4 + quad) ^ x7) << 3]);
      if (C0) s0[tb] = __builtin_amdgcn_mfma_f32_16x16x32_bf16(kf, qf[0][hh], s0[tb], 0, 0, 0);
      s1[tb] = __builtin_amdgcn_mfma_f32_16x16x32_bf16(kf, qf[1][hh], s1[tb], 0, 0, 0);
    }
  // PV(t-1): independent MFMA stream; softmax(t) VALU overlaps its completion.
  if (PVV) {
    #pragma unroll
    for (int db = 0; db < 4; db++)
      #pragma unroll
      for (int tp = 0; tp < 2; tp++) {
        bf16x8 vf = *reinterpret_cast<const bf16x8*>(
            &Vp[db * 16 + l15][((tp * 4 + quad) ^ x7) << 3]);
        if (PV0) accO[0][db] = __builtin_amdgcn_mfma_f32_16x16x32_bf16(vf, pb0[tp], accO[0][db], 0, 0, 0);
        accO[1][db] = __builtin_amdgcn_mfma_f32_16x16x32_bf16(vf, pb1[tp], accO[1][db], 0, 0, 0);
      }
  }
  __builtin_amdgcn_s_setprio(0);
  // softmax(t) + pack into Pt (consumed at step t+1 / epilogue)
  if (C0) soft_pack<M0>(s0, lsum[0], p0row, quad, tmb);
  soft_pack<M1>(s1, lsum[1], p1row, quad, tmb);
}

// ---- flash attention, paired-supertile balanced blocks + deferred-PV pipeline.
// XCD-grouped remap (512 blocks, grid (16,32), n = x + 16*y):
//   g = n&7 (XCD), idx = n>>3, p = idx&15, bh = g*4 + (idx>>4)  [idx>>4 in 0..3]
// -> bijective onto (p in [0,16), bh in [0,32)); all 16 p-blocks of one bh land
// on XCD g; 4 bh per XCD = 2MB K/V inside one 4MB XCD L2.
// (R10's p-complement variant: +3.8us, reverted. R11's qkv prep-fusion:
//  LDS 98.8KB -> 1 block/CU, 3x regression, reverted.)
// block handles q-supertiles st0=p and st1=31-p (constant 33 tile-sides).
// Triple-buffered K/V LDS: iter t reads K[t%3] (QK) and V[(t-1)%3] (deferred PV),
// stages t+1 into (t+1)%3. One barrier per iter; PV off the critical chain.
// g2r staging uses pointer increments (constant stride/step).
__global__ __launch_bounds__(256) void attn_k(
    const unsigned short* __restrict__ q,
    const unsigned short* __restrict__ k,
    const unsigned short* __restrict__ vt,
    unsigned short* __restrict__ y) {
  __shared__ __attribute__((aligned(16))) unsigned short Kl[3][64][64];
  __shared__ __attribute__((aligned(16))) unsigned short Vl[3][64][64];
  __shared__ __attribute__((aligned(16))) unsigned short Pt[4][16][152];

  // bijective XCD-locality remap (512 blocks)
  int n = blockIdx.x + 16 * blockIdx.y;
  int g = n & 7, idx = n >> 3;
  int p = idx & 15;                   // 0..15
  int bh = g * 4 + (idx >> 4);        // idx>>4 in [0,4) -> bh in [0,32)
  int st0 = p, st1 = 31 - p;          // st0 < 16 <= st1
  int b = bh >> 4, h = bh & 15;
  const unsigned short* Q0 = q + ((size_t)bh * SEQ + st0 * 64) * HS;
  const unsigned short* Q1 = q + ((size_t)bh * SEQ + st1 * 64) * HS;
  const unsigned short* K  = k  + (size_t)bh * SEQ * HS;
  const unsigned short* V  = vt + (size_t)bh * HS * SEQ;   // [d][s]
  int tid = threadIdx.x, wave = tid >> 6, lane = tid & 63;
  int quad = lane >> 4, l15 = lane & 15;
  int lr = tid >> 3, lc = (tid & 7) * 8;
  int sc = (((tid & 7) ^ (lr & 7)) << 3);        // swizzled LDS chunk offset

  bf16x8 qf[2][2];
  #pragma unroll
  for (int hh = 0; hh < 2; hh++) {
    qf[0][hh] = *reinterpret_cast<const bf16x8*>(
        &Q0[(size_t)(wave * 16 + l15) * HS + hh * 32 + quad * 8]);
    qf[1][hh] = *reinterpret_cast<const bf16x8*>(
        &Q1[(size_t)(wave * 16 + l15) * HS + hh * 32 + quad * 8]);
  }

  f32x4 lsum[2] = {(f32x4){0,0,0,0}, (f32x4){0,0,0,0}};
  f32x4 accO[2][4];
  #pragma unroll
  for (int f = 0; f < 2; f++)
    #pragma unroll
    for (int i = 0; i < 4; i++) accO[f][i] = (f32x4){0.f, 0.f, 0.f, 0.f};

  unsigned short* p0row = &Pt[wave][l15][0];
  unsigned short* p1row = &Pt[wave][l15][64];
  int tmb = -(wave * 16 + l15);

  // staging pointers, advanced by constant stride per kv-tile
  const unsigned short* pK0 = K + (size_t)lr * HS + lc;
  const unsigned short* pK1 = pK0 + (size_t)32 * HS;
  const unsigned short* pV0 = V + (size_t)lr * SEQ + lc;
  const unsigned short* pV1 = pV0 + (size_t)32 * SEQ;
  uint4 kr0, kr1, vr0, vr1;
  auto g2r = [&]() {
    kr0 = *(const uint4*)pK0; kr1 = *(const uint4*)pK1;
    vr0 = *(const uint4*)pV0; vr1 = *(const uint4*)pV1;
    pK0 += 64 * HS; pK1 += 64 * HS; pV0 += 64; pV1 += 64;
  };
  auto r2l = [&](int nb) {
    *(uint4*)&Kl[nb][lr][sc] = kr0; *(uint4*)&Kl[nb][lr + 32][sc] = kr1;
    *(uint4*)&Vl[nb][lr][sc] = vr0; *(uint4*)&Vl[nb][lr + 32][sc] = vr1;
  };

  g2r(); r2l(0);
  __syncthreads();

  // ---- t = 0: QK/SM only (no PV yet)
  {
    if (st1 > 0) g2r();
    if (st0 == 0)
      attn_step<1, false, false>(Kl[0], Vl[2], p0row, p1row, qf, lsum, accO, quad, l15, tmb);
    else
      attn_step<0, false, false>(Kl[0], Vl[2], p0row, p1row, qf, lsum, accO, quad, l15, tmb);
    if (st1 > 0) r2l(1);
    __syncthreads();
  }
  // ---- t = 1 .. st0-1 : both sides QK free, PV both
  for (int t = 1; t < st0; t++) {
    g2r();
    attn_step<0, true, true>(Kl[t % 3], Vl[(t + 2) % 3], p0row, p1row, qf, lsum, accO, quad, l15, tmb);
    r2l((t + 1) % 3);
    __syncthreads();
  }
  // ---- t = st0 (if >=1): side0 masked QK, PV both
  if (st0 >= 1) {
    int t = st0;
    g2r();
    attn_step<1, true, true>(Kl[t % 3], Vl[(t + 2) % 3], p0row, p1row, qf, lsum, accO, quad, l15, tmb);
    r2l((t + 1) % 3);
    __syncthreads();
  }
  // ---- t = st0+1: side1-only QK (masked iff == st1), side0's LAST PV
  {
    int t = st0 + 1;
    bool more = (t < st1);
    if (more) g2r();
    if (t == st1)
      attn_step<3, true, true>(Kl[t % 3], Vl[(t + 2) % 3], p0row, p1row, qf, lsum, accO, quad, l15, tmb);
    else
      attn_step<2, true, true>(Kl[t % 3], Vl[(t + 2) % 3], p0row, p1row, qf, lsum, accO, quad, l15, tmb);
    if (more) r2l((t + 1) % 3);
    __syncthreads();
  }
  // ---- t = st0+2 .. st1-1 : side1 only
  for (int t = st0 + 2; t < st1; t++) {
    g2r();
    attn_step<2, false, true>(Kl[t % 3], Vl[(t + 2) % 3], p0row, p1row, qf, lsum, accO, quad, l15, tmb);
    r2l((t + 1) % 3);
    __syncthreads();
  }
  // ---- t = st1 (if not already done above): masked side1 QK, PV side1
  if (st1 >= st0 + 2) {
    int t = st1;
    attn_step<3, false, true>(Kl[t % 3], Vl[(t + 2) % 3], p0row, p1row, qf, lsum, accO, quad, l15, tmb);
  }
  // ---- epilogue PV for side1's last tile: read P(st1) back, multiply V(st1)
  {
    const unsigned short (&Vb)[64][64] = Vl[st1 % 3];
    int x7 = l15 & 7;
    bf16x8 pb1[2];
    #pragma unroll
    for (int tp = 0; tp < 2; tp++)
      pb1[tp] = *reinterpret_cast<const bf16x8*>(&p1row[tp * 32 + quad * 8]);
    #pragma unroll
    for (int db = 0; db < 4; db++)
      #pragma unroll
      for (int tp = 0; tp < 2; tp++) {
        bf16x8 vf = *reinterpret_cast<const bf16x8*>(
            &Vb[db * 16 + l15][((tp * 4 + quad) ^ x7) << 3]);
        accO[1][db] = __builtin_amdgcn_mfma_f32_16x16x32_bf16(vf, pb1[tp], accO[1][db], 0, 0, 0);
      }
  }

  // epilogue: horizontal lsum, reduce over quads, normalize, write both sides
  #pragma unroll
  for (int f = 0; f < 2; f++) {
    float rs = (lsum[f][0] + lsum[f][1]) + (lsum[f][2] + lsum[f][3]);
    rs += __shfl_xor(rs, 16); rs += __shfl_xor(rs, 32);
    float inv = 1.0f / fmaxf(rs, 1e-30f);
    int srow = (f == 0 ? st0 : st1) * 64 + wave * 16 + l15;
    #pragma unroll
    for (int db = 0; db < 4; db++) {
      ushort4 pk;
      pk.x = f2bf(accO[f][db][0] * inv); pk.y = f2bf(accO[f][db][1] * inv);
      pk.z = f2bf(accO[f][db][2] * inv); pk.w = f2bf(accO[f][db][3] * inv);
      *(ushort4*)&y[((size_t)b * SEQ + srow) * HDIM + h * 64 + db * 16 + quad * 4] = pk;
    }
  }
}

// ---- output projection, 128x64 tile, dbuf issue-early, 1 barrier/step ----
__global__ __launch_bounds__(256) void out_gemm(
    const unsigned short* __restrict__ y,
    const unsigned short* __restrict__ wot,
    const void* __restrict__ bo,
    float* __restrict__ out) {
  __shared__ __attribute__((aligned(16))) unsigned short Al[2][128 * 64];
  __shared__ __attribute__((aligned(16))) unsigned short Bl[2][64 * 64];
  int tid = threadIdx.x;
  int fbo = detect_flag_block(bo, 512, tid, 256);
  int mt = blockIdx.x, nt = blockIdx.y;
  const unsigned short* A  = y   + (size_t)mt * 128 * HDIM;
  const unsigned short* Bm = wot + (size_t)nt * 64 * HDIM;
  int wave = tid >> 6, lane = tid & 63;
  int quad = lane >> 4, l15 = lane & 15;
  int r8 = lane >> 3, c8 = lane & 7;
  int gcol = ((c8 ^ r8) << 3);
  int x7 = l15 & 7;
  int wm = (wave >> 1) * 64, wn = (wave & 1) * 32;
  f32x4 acc[4][2];
  #pragma unroll
  for (int i = 0; i < 4; i++)
    #pragma unroll
    for (int j = 0; j < 2; j++) acc[i][j] = (f32x4){0.f, 0.f, 0.f, 0.f};

  auto stage = [&](int bb, int k0) {
    #pragma unroll
    for (int c = 0; c < 4; c++) {
      int row = wave * 32 + c * 8 + r8;
      gl_lds16(&A[(size_t)row * HDIM + k0 + gcol], &Al[bb][(wave * 32 + c * 8) * 64]);
    }
    #pragma unroll
    for (int c = 0; c < 2; c++) {
      int row = wave * 16 + c * 8 + r8;
      gl_lds16(&Bm[(size_t)row * HDIM + k0 + gcol], &Bl[bb][(wave * 16 + c * 8) * 64]);
    }
  };

  stage(0, 0);
  __syncthreads();
  for (int ks = 0; ks < 16; ks++) {
    int bb = ks & 1;
    if (ks < 15) stage(bb ^ 1, (ks + 1) * 64);   // issue-early
    #pragma unroll
    for (int h = 0; h < 2; h++) {
      int cq = ((quad + 4 * h) ^ x7) << 3;
      bf16x8 af[4], bfr[2];
      #pragma unroll
      for (int fm = 0; fm < 4; fm++)
        af[fm] = *reinterpret_cast<const bf16x8*>(&Al[bb][(wm + fm * 16 + l15) * 64 + cq]);
      #pragma unroll
      for (int fn = 0; fn < 2; fn++)
        bfr[fn] = *reinterpret_cast<const bf16x8*>(&Bl[bb][(wn + fn * 16 + l15) * 64 + cq]);
      __builtin_amdgcn_s_setprio(1);
      #pragma unroll
      for (int fm = 0; fm < 4; fm++)
        #pragma unroll
        for (int fn = 0; fn < 2; fn++)
          acc[fm][fn] = __builtin_amdgcn_mfma_f32_16x16x32_bf16(af[fm], bfr[fn], acc[fm][fn], 0, 0, 0);
      __builtin_amdgcn_s_setprio(0);
    }
    __syncthreads();
  }

  #pragma unroll
  for (int fn = 0; fn < 2; fn++) {
    int n = nt * 64 + wn + fn * 16 + l15;
    float bias = load_elem(bo, fbo, n);
    #pragma unroll
    for (int fm = 0; fm < 4; fm++) {
      int m = mt * 128 + wm + fm * 16 + quad * 4;
      #pragma unroll
      for (int r = 0; r < 4; r++)
        out[(size_t)(m + r) * CH + n] = acc[fm][fn][r] + bias;
    }
  }
}

extern "C" void kernel_launch(void* const* d_in, const int* in_sizes, int n_in,
                              void* d_out, int out_size, void* d_ws, size_t ws_size,
                              hipStream_t stream) {
  const void* x  = d_in[0];
  const void* Wq = d_in[1];
  const void* Wk = d_in[2];
  const void* Wv = d_in[3];
  const void* Wo = d_in[4];
  const void* bo = d_in[5];
  float* out = (float*)d_out;

  char* ws = (char*)d_ws;
  const size_t MB = 1024 * 1024;
  unsigned short* qb   = (unsigned short*)(ws + 0);        // [B,H,S,D]  8MB (pre-scaled)
  unsigned short* kb   = (unsigned short*)(ws + 8  * MB);  // [B,H,S,D]  8MB
  unsigned short* vtb  = (unsigned short*)(ws + 16 * MB);  // [B,H,D,S]  8MB
  unsigned short* yb   = (unsigned short*)(ws + 24 * MB);  // [B,S,HD]   8MB
  unsigned short* wall = (unsigned short*)(ws + 32 * MB);  // [3][H,D,C] 6MB contiguous
  unsigned short* wot  = (unsigned short*)(ws + 38 * MB);  // [C,HD]     2MB
  unsigned short* xb   = (unsigned short*)(ws + 40 * MB);  // [B,S,C]    8MB bf16

  prep<<<5120, 256, 0, stream>>>(x, Wq, Wk, Wv, Wo, xb, wall, wot);
  qkv_gemm<<<dim3(NB * SEQ / 128, 3 * HDIM / 192), 256, 0, stream>>>(xb, wall, qb, kb, vtb);
  attn_k<<<dim3(16, NB * NH), 256, 0, stream>>>(qb, kb, vtb, yb);
  out_gemm<<<dim3(NB * SEQ / 128, CH / 64), 256, 0, stream>>>(yb, wot, bo, out);
}

// Round 13
// 165.745 us; speedup vs baseline: 1.5260x; 1.0170x over previous
//
#include <hip/hip_runtime.h>
#include <cstdint>
#include <cstddef>

constexpr int SEQ  = 2048;
constexpr int CH   = 1024;
constexpr int NH   = 16;
constexpr int HS   = 64;
constexpr int NB   = 2;
constexpr int HDIM = NH * HS; // 1024

typedef __bf16 bf16x8 __attribute__((ext_vector_type(8)));
typedef __bf16 bf16x4 __attribute__((ext_vector_type(4)));
typedef float  f32x4  __attribute__((ext_vector_type(4)));

__device__ __forceinline__ unsigned short f2bf(float f) {
  union { float f; unsigned u; } v; v.f = f;
  unsigned u = v.u;
  u += 0x7fffu + ((u >> 16) & 1u);   // RNE
  return (unsigned short)(u >> 16);
}
__device__ __forceinline__ float bf2f(unsigned short h) {
  union { unsigned u; float f; } v; v.u = ((unsigned)h) << 16;
  return v.f;
}
__device__ __forceinline__ float load_elem(const void* p, int flag, size_t idx) {
  if (flag) return ((const float*)p)[idx];
  return bf2f(((const unsigned short*)p)[idx]);
}
__device__ __forceinline__ void gl_lds16(const unsigned short* g, unsigned short* l) {
  __builtin_amdgcn_global_load_lds(
      (const __attribute__((address_space(1))) unsigned int*)g,
      (__attribute__((address_space(3))) unsigned int*)l, 16, 0, 0);
}

// ---- inline dtype detector (observed: inputs fp32; kept as insurance) ----
__device__ int detect_flag_block(const void* p, int n, int tid, int nthr) {
  __shared__ int det_good;
  if (tid == 0) det_good = 0;
  __syncthreads();
  const unsigned short* u = (const unsigned short*)p;
  int good = 0;
  for (int j = tid; j < n; j += nthr) {
    unsigned short v = u[2 * j];
    int e = (v >> 7) & 0xFF;
    if (v != 0 && e >= 90 && e <= 150) good++;
  }
  atomicAdd(&det_good, good);
  __syncthreads();
  return (det_good * 10 >= n * 7) ? 0 : 1;   // 0 = bf16, 1 = fp32
}

// ---- fused preprocessing: ingest x + transpose Wq/Wk/Wv + transpose Wo ----
// weight blocks process TWO paired sub-tiles (same rows r0, both 32-col
// halves): one detector scan + two transpose passes -> grid 5120 -> 3072.
// Even-index pairing provably never straddles which/hh/r0 boundaries.
__global__ __launch_bounds__(256) void prep(
    const void* __restrict__ x,  const void* __restrict__ wq,
    const void* __restrict__ wk, const void* __restrict__ wv,
    const void* __restrict__ wo,
    unsigned short* __restrict__ xb,
    unsigned short* __restrict__ wall,   // [3][H][D][C]
    unsigned short* __restrict__ wot) {  // [C][HD]
  __shared__ unsigned short tile[32][36];   // stride 36 elems (72B), 8B-aligned cols
  int idx = blockIdx.x, tid = threadIdx.x;
  int row = tid >> 3, cg = (tid & 7) * 4;   // load mapping: 32 rows x 8 col-groups
  int col = tid >> 3, rg = (tid & 7) * 4;   // store mapping: 32 cols x 8 row-groups
  if (idx < 1024) {
    int f = detect_flag_block(x, 512, tid, 256);
    size_t n4 = (size_t)NB * SEQ * CH / 4;
    for (size_t i = (size_t)idx * 256 + tid; i < n4; i += (size_t)1024 * 256) {
      ushort4 o;
      if (f) {
        float4 v = ((const float4*)x)[i];
        o.x = f2bf(v.x); o.y = f2bf(v.y); o.z = f2bf(v.z); o.w = f2bf(v.w);
      } else {
        o = ((const ushort4*)x)[i];
      }
      ((ushort4*)xb)[i] = o;
    }
  } else if (idx < 2560) {
    int o = (idx - 1024) * 2;       // 0..3070, even -> pair (o, o+1)
    int which = o >> 10, hh = (o >> 6) & 15, sub = o & 63;
    const void* src = (which == 0) ? wq : (which == 1) ? wk : wv;
    int f = detect_flag_block(src, 512, tid, 256);
    int r0 = (sub >> 1) * 32;       // over CH (1024); same for both pair halves
    size_t boff = (size_t)hh * CH * HS;
    unsigned short* d = wall + ((size_t)which * NH + hh) * HS * CH;
    #pragma unroll
    for (int t = 0; t < 2; t++) {
      int c0 = t * 32;              // over HS (64): both halves
      size_t si = boff + (size_t)(r0 + row) * HS + c0 + cg;
      ushort4 t4;
      if (f) {
        float4 v = *(const float4*)((const float*)src + si);
        t4.x = f2bf(v.x); t4.y = f2bf(v.y); t4.z = f2bf(v.z); t4.w = f2bf(v.w);
      } else {
        t4 = *(const ushort4*)((const unsigned short*)src + si);
      }
      *(ushort4*)&tile[row][cg] = t4;
      __syncthreads();
      ushort4 ot;
      ot.x = tile[rg + 0][col]; ot.y = tile[rg + 1][col];
      ot.z = tile[rg + 2][col]; ot.w = tile[rg + 3][col];
      *(ushort4*)&d[(size_t)(c0 + col) * CH + r0 + rg] = ot;
      if (t == 0) __syncthreads();  // tile reused by second half
    }
  } else {
    int o = (idx - 2560) * 2;       // 0..1022, even -> pair (o, o+1)
    int f = detect_flag_block(wo, 512, tid, 256);
    int r0 = (o >> 5) * 32;         // over HDIM (rows); same for both halves
    int c0base = (o & 31) * 32;     // over CH (cols); halves are c0base, c0base+32
    #pragma unroll
    for (int t = 0; t < 2; t++) {
      int c0 = c0base + t * 32;
      size_t si = (size_t)(r0 + row) * CH + c0 + cg;
      ushort4 t4;
      if (f) {
        float4 v = *(const float4*)((const float*)wo + si);
        t4.x = f2bf(v.x); t4.y = f2bf(v.y); t4.z = f2bf(v.z); t4.w = f2bf(v.w);
      } else {
        t4 = *(const ushort4*)((const unsigned short*)wo + si);
      }
      *(ushort4*)&tile[row][cg] = t4;
      __syncthreads();
      ushort4 ot;
      ot.x = tile[rg + 0][col]; ot.y = tile[rg + 1][col];
      ot.z = tile[rg + 2][col]; ot.w = tile[rg + 3][col];
      *(ushort4*)&wot[(size_t)(c0 + col) * HDIM + r0 + rg] = ot;
      if (t == 0) __syncthreads();
    }
  }
}

// ---- fused QKV GEMM: 128x192 tile, dbuf issue-early staging, 1 barrier/step.
// grid (32,16)=512 blocks = exactly 2/CU (one full round); LDS 80KB -> 2 resident.
__global__ __launch_bounds__(256, 2) void qkv_gemm(
    const unsigned short* __restrict__ xb,
    const unsigned short* __restrict__ wall,   // [3072][1024]
    unsigned short* __restrict__ qo,
    unsigned short* __restrict__ ko,
    unsigned short* __restrict__ vt) {
  __shared__ __attribute__((aligned(16))) unsigned short Al[2][128 * 64];
  __shared__ __attribute__((aligned(16))) unsigned short Bl[2][192 * 64];
  int mt = blockIdx.x, nt = blockIdx.y;
  const unsigned short* A  = xb   + (size_t)mt * 128 * CH;
  const unsigned short* Bm = wall + (size_t)nt * 192 * CH;
  int tid = threadIdx.x, wave = tid >> 6, lane = tid & 63;
  int quad = lane >> 4, l15 = lane & 15;
  int r8 = lane >> 3, c8 = lane & 7;
  int gcol = ((c8 ^ r8) << 3);
  int x7 = l15 & 7;
  int wm = (wave >> 1) * 64, wn = (wave & 1) * 96;
  f32x4 acc[4][6];
  #pragma unroll
  for (int i = 0; i < 4; i++)
    #pragma unroll
    for (int j = 0; j < 6; j++) acc[i][j] = (f32x4){0.f, 0.f, 0.f, 0.f};

  auto stage = [&](int bb, int k0) {
    #pragma unroll
    for (int c = 0; c < 4; c++) {
      int row = wave * 32 + c * 8 + r8;
      gl_lds16(&A[(size_t)row * CH + k0 + gcol], &Al[bb][(wave * 32 + c * 8) * 64]);
    }
    #pragma unroll
    for (int c = 0; c < 6; c++) {
      int row = wave * 48 + c * 8 + r8;
      gl_lds16(&Bm[(size_t)row * CH + k0 + gcol], &Bl[bb][(wave * 48 + c * 8) * 64]);
    }
  };

  stage(0, 0);
  __syncthreads();
  for (int ks = 0; ks < 16; ks++) {
    int bb = ks & 1;
    if (ks < 15) stage(bb ^ 1, (ks + 1) * 64);   // issue-early: latency hides under MFMA
    #pragma unroll
    for (int h = 0; h < 2; h++) {
      int cq = ((quad + 4 * h) ^ x7) << 3;
      bf16x8 af[4], bfr[6];
      #pragma unroll
      for (int fm = 0; fm < 4; fm++)
        af[fm] = *reinterpret_cast<const bf16x8*>(&Al[bb][(wm + fm * 16 + l15) * 64 + cq]);
      #pragma unroll
      for (int fn = 0; fn < 6; fn++)
        bfr[fn] = *reinterpret_cast<const bf16x8*>(&Bl[bb][(wn + fn * 16 + l15) * 64 + cq]);
      __builtin_amdgcn_s_setprio(1);
      #pragma unroll
      for (int fm = 0; fm < 4; fm++)
        #pragma unroll
        for (int fn = 0; fn < 6; fn++)
          acc[fm][fn] = __builtin_amdgcn_mfma_f32_16x16x32_bf16(af[fm], bfr[fn], acc[fm][fn], 0, 0, 0);
      __builtin_amdgcn_s_setprio(0);
    }
    __syncthreads();
  }

  // epilogue: per-fragment q/k/v segment selection (192-col tile straddles
  // the 1024-col boundaries; seg is lane-uniform per fragment since
  // boundaries are 16-aligned)
  #pragma unroll
  for (int fn = 0; fn < 6; fn++) {
    int c0 = nt * 192 + wn + fn * 16;
    int seg = c0 >> 10;
    int hd = (c0 & 1023) + l15;
    int h = hd >> 6, d = hd & 63;
    if (seg < 2) {
      unsigned short* dst = (seg == 0) ? qo : ko;
      float s = (seg == 0) ? 0.18033688011112042f : 1.0f;  // 0.125*log2(e) folded into q
      #pragma unroll
      for (int fm = 0; fm < 4; fm++) {
        int m = mt * 128 + wm + fm * 16 + quad * 4;
        int b = m >> 11, s0 = m & 2047;
        #pragma unroll
        for (int r = 0; r < 4; r++)
          dst[(((size_t)b * NH + h) * SEQ + s0 + r) * HS + d] = f2bf(acc[fm][fn][r] * s);
      }
    } else { // v transposed: vt[b][h][d][s]
      #pragma unroll
      for (int fm = 0; fm < 4; fm++) {
        int m = mt * 128 + wm + fm * 16 + quad * 4;
        int b = m >> 11, s0 = m & 2047;
        ushort4 pk;
        pk.x = f2bf(acc[fm][fn][0]); pk.y = f2bf(acc[fm][fn][1]);
        pk.z = f2bf(acc[fm][fn][2]); pk.w = f2bf(acc[fm][fn][3]);
        *(ushort4*)&vt[(((size_t)b * NH + h) * HS + d) * SEQ + s0] = pk;
      }
    }
  }
}

// ---- softmax + P^T pack for one fragment (S^T C-layout in regs) ----
template <bool MASKED>
__device__ __forceinline__ void soft_pack(const f32x4* s, f32x4& ls,
                                          unsigned short* ptRow, int quad, int tmb) {
  #pragma unroll
  for (int tb = 0; tb < 4; tb++) {
    f32x4 pv;
    #pragma unroll
    for (int r = 0; r < 4; r++) {
      float p = __builtin_amdgcn_exp2f(s[tb][r]);
      if (MASKED) { if (tmb + tb * 16 + quad * 4 + r > 0) p = 0.f; }
      pv[r] = p;
    }
    ls += pv;
    bf16x4 pk;
    pk.x = (__bf16)pv[0]; pk.y = (__bf16)pv[1];
    pk.z = (__bf16)pv[2]; pk.w = (__bf16)pv[3];
    *(bf16x4*)&ptRow[tb * 16 + quad * 4] = pk;
  }
}

// ---- one pipeline step: read P(t-1) from Pt FIRST (write completed under the
// previous barrier -> no write->read turnaround stall), then QK(t) + PV(t-1)
// as interleaved MFMA streams, then softmax(t) -> Pt.
// QKM: 0 = both sides free; 1 = side0 masked + side1 free;
//      2 = side1 only, free; 3 = side1 only, masked.
// PV0: side0 PV active. PVV: any PV this step (false only at t=0).
// K/V tiles XOR-swizzled: 16B chunk c of row r at chunk c^(r&7).
template <int QKM, bool PV0, bool PVV>
__device__ __forceinline__ void attn_step(
    const unsigned short (&Kb)[64][64], const unsigned short (&Vp)[64][64],
    unsigned short* p0row, unsigned short* p1row,
    const bf16x8 (&qf)[2][2], f32x4 (&lsum)[2], f32x4 (&accO)[2][4],
    int quad, int l15, int tmb) {
  constexpr bool C0 = (QKM <= 1);
  constexpr bool M0 = (QKM == 1);
  constexpr bool M1 = (QKM == 3);
  int x7 = l15 & 7;
  // read P(t-1) fragments (issued early; latency hides under K reads + MFMA)
  bf16x8 pb0[2], pb1[2];
  if (PVV) {
    #pragma unroll
    for (int tp = 0; tp < 2; tp++) {
      if (PV0) pb0[tp] = *reinterpret_cast<const bf16x8*>(&p0row[tp * 32 + quad * 8]);
      pb1[tp] = *reinterpret_cast<const bf16x8*>(&p1row[tp * 32 + quad * 8]);
    }
  }
  f32x4 s0[4], s1[4];
  #pragma unroll
  for (int tb = 0; tb < 4; tb++) { s0[tb] = (f32x4){0,0,0,0}; s1[tb] = (f32x4){0,0,0,0}; }
  __builtin_amdgcn_s_setprio(1);
  // QK(t)
  #pragma unroll
  for (int tb = 0; tb < 4; tb++)
    #pragma unroll
    for (int hh = 0; hh < 2; hh++) {
      bf16x8 kf = *reinterpret_cast<const bf16x8*>(
          &Kb[tb * 16 + l15][((hh * 4 + quad) ^ x7) << 3]);
      if (C0) s0[tb] = __builtin_amdgcn_mfma_f32_16x16x32_bf16(kf, qf[0][hh], s0[tb], 0, 0, 0);
      s1[tb] = __builtin_amdgcn_mfma_f32_16x16x32_bf16(kf, qf[1][hh], s1[tb], 0, 0, 0);
    }
  // PV(t-1): independent MFMA stream; softmax(t) VALU overlaps its completion.
  if (PVV) {
    #pragma unroll
    for (int db = 0; db < 4; db++)
      #pragma unroll
      for (int tp = 0; tp < 2; tp++) {
        bf16x8 vf = *reinterpret_cast<const bf16x8*>(
            &Vp[db * 16 + l15][((tp * 4 + quad) ^ x7) << 3]);
        if (PV0) accO[0][db] = __builtin_amdgcn_mfma_f32_16x16x32_bf16(vf, pb0[tp], accO[0][db], 0, 0, 0);
        accO[1][db] = __builtin_amdgcn_mfma_f32_16x16x32_bf16(vf, pb1[tp], accO[1][db], 0, 0, 0);
      }
  }
  __builtin_amdgcn_s_setprio(0);
  // softmax(t) + pack into Pt (consumed at step t+1 / epilogue)
  if (C0) soft_pack<M0>(s0, lsum[0], p0row, quad, tmb);
  soft_pack<M1>(s1, lsum[1], p1row, quad, tmb);
}

// ---- flash attention, paired-supertile balanced blocks + deferred-PV pipeline.
// XCD-grouped remap (512 blocks, grid (16,32), n = x + 16*y):
//   g = n&7 (XCD), idx = n>>3, p = idx&15, bh = g*4 + (idx>>4)  [idx>>4 in 0..3]
// -> bijective onto (p in [0,16), bh in [0,32)); all 16 p-blocks of one bh land
// on XCD g; 4 bh per XCD = 2MB K/V inside one 4MB XCD L2.
// (R10's p-complement variant: +3.8us, reverted. R11's qkv prep-fusion:
//  LDS 98.8KB -> 1 block/CU, 3x regression, reverted.)
// block handles q-supertiles st0=p and st1=31-p (constant 33 tile-sides).
// Triple-buffered K/V LDS: iter t reads K[t%3] (QK) and V[(t-1)%3] (deferred PV),
// stages t+1 into (t+1)%3. One barrier per iter; PV off the critical chain.
// g2r staging uses pointer increments (constant stride/step).
__global__ __launch_bounds__(256) void attn_k(
    const unsigned short* __restrict__ q,
    const unsigned short* __restrict__ k,
    const unsigned short* __restrict__ vt,
    unsigned short* __restrict__ y) {
  __shared__ __attribute__((aligned(16))) unsigned short Kl[3][64][64];
  __shared__ __attribute__((aligned(16))) unsigned short Vl[3][64][64];
  __shared__ __attribute__((aligned(16))) unsigned short Pt[4][16][152];

  // bijective XCD-locality remap (512 blocks)
  int n = blockIdx.x + 16 * blockIdx.y;
  int g = n & 7, idx = n >> 3;
  int p = idx & 15;                   // 0..15
  int bh = g * 4 + (idx >> 4);        // idx>>4 in [0,4) -> bh in [0,32)
  int st0 = p, st1 = 31 - p;          // st0 < 16 <= st1
  int b = bh >> 4, h = bh & 15;
  const unsigned short* Q0 = q + ((size_t)bh * SEQ + st0 * 64) * HS;
  const unsigned short* Q1 = q + ((size_t)bh * SEQ + st1 * 64) * HS;
  const unsigned short* K  = k  + (size_t)bh * SEQ * HS;
  const unsigned short* V  = vt + (size_t)bh * HS * SEQ;   // [d][s]
  int tid = threadIdx.x, wave = tid >> 6, lane = tid & 63;
  int quad = lane >> 4, l15 = lane & 15;
  int lr = tid >> 3, lc = (tid & 7) * 8;
  int sc = (((tid & 7) ^ (lr & 7)) << 3);        // swizzled LDS chunk offset

  bf16x8 qf[2][2];
  #pragma unroll
  for (int hh = 0; hh < 2; hh++) {
    qf[0][hh] = *reinterpret_cast<const bf16x8*>(
        &Q0[(size_t)(wave * 16 + l15) * HS + hh * 32 + quad * 8]);
    qf[1][hh] = *reinterpret_cast<const bf16x8*>(
        &Q1[(size_t)(wave * 16 + l15) * HS + hh * 32 + quad * 8]);
  }

  f32x4 lsum[2] = {(f32x4){0,0,0,0}, (f32x4){0,0,0,0}};
  f32x4 accO[2][4];
  #pragma unroll
  for (int f = 0; f < 2; f++)
    #pragma unroll
    for (int i = 0; i < 4; i++) accO[f][i] = (f32x4){0.f, 0.f, 0.f, 0.f};

  unsigned short* p0row = &Pt[wave][l15][0];
  unsigned short* p1row = &Pt[wave][l15][64];
  int tmb = -(wave * 16 + l15);

  // staging pointers, advanced by constant stride per kv-tile
  const unsigned short* pK0 = K + (size_t)lr * HS + lc;
  const unsigned short* pK1 = pK0 + (size_t)32 * HS;
  const unsigned short* pV0 = V + (size_t)lr * SEQ + lc;
  const unsigned short* pV1 = pV0 + (size_t)32 * SEQ;
  uint4 kr0, kr1, vr0, vr1;
  auto g2r = [&]() {
    kr0 = *(const uint4*)pK0; kr1 = *(const uint4*)pK1;
    vr0 = *(const uint4*)pV0; vr1 = *(const uint4*)pV1;
    pK0 += 64 * HS; pK1 += 64 * HS; pV0 += 64; pV1 += 64;
  };
  auto r2l = [&](int nb) {
    *(uint4*)&Kl[nb][lr][sc] = kr0; *(uint4*)&Kl[nb][lr + 32][sc] = kr1;
    *(uint4*)&Vl[nb][lr][sc] = vr0; *(uint4*)&Vl[nb][lr + 32][sc] = vr1;
  };

  g2r(); r2l(0);
  __syncthreads();

  // ---- t = 0: QK/SM only (no PV yet)
  {
    if (st1 > 0) g2r();
    if (st0 == 0)
      attn_step<1, false, false>(Kl[0], Vl[2], p0row, p1row, qf, lsum, accO, quad, l15, tmb);
    else
      attn_step<0, false, false>(Kl[0], Vl[2], p0row, p1row, qf, lsum, accO, quad, l15, tmb);
    if (st1 > 0) r2l(1);
    __syncthreads();
  }
  // ---- t = 1 .. st0-1 : both sides QK free, PV both
  for (int t = 1; t < st0; t++) {
    g2r();
    attn_step<0, true, true>(Kl[t % 3], Vl[(t + 2) % 3], p0row, p1row, qf, lsum, accO, quad, l15, tmb);
    r2l((t + 1) % 3);
    __syncthreads();
  }
  // ---- t = st0 (if >=1): side0 masked QK, PV both
  if (st0 >= 1) {
    int t = st0;
    g2r();
    attn_step<1, true, true>(Kl[t % 3], Vl[(t + 2) % 3], p0row, p1row, qf, lsum, accO, quad, l15, tmb);
    r2l((t + 1) % 3);
    __syncthreads();
  }
  // ---- t = st0+1: side1-only QK (masked iff == st1), side0's LAST PV
  {
    int t = st0 + 1;
    bool more = (t < st1);
    if (more) g2r();
    if (t == st1)
      attn_step<3, true, true>(Kl[t % 3], Vl[(t + 2) % 3], p0row, p1row, qf, lsum, accO, quad, l15, tmb);
    else
      attn_step<2, true, true>(Kl[t % 3], Vl[(t + 2) % 3], p0row, p1row, qf, lsum, accO, quad, l15, tmb);
    if (more) r2l((t + 1) % 3);
    __syncthreads();
  }
  // ---- t = st0+2 .. st1-1 : side1 only
  for (int t = st0 + 2; t < st1; t++) {
    g2r();
    attn_step<2, false, true>(Kl[t % 3], Vl[(t + 2) % 3], p0row, p1row, qf, lsum, accO, quad, l15, tmb);
    r2l((t + 1) % 3);
    __syncthreads();
  }
  // ---- t = st1 (if not already done above): masked side1 QK, PV side1
  if (st1 >= st0 + 2) {
    int t = st1;
    attn_step<3, false, true>(Kl[t % 3], Vl[(t + 2) % 3], p0row, p1row, qf, lsum, accO, quad, l15, tmb);
  }
  // ---- epilogue PV for side1's last tile: read P(st1) back, multiply V(st1)
  {
    const unsigned short (&Vb)[64][64] = Vl[st1 % 3];
    int x7 = l15 & 7;
    bf16x8 pb1[2];
    #pragma unroll
    for (int tp = 0; tp < 2; tp++)
      pb1[tp] = *reinterpret_cast<const bf16x8*>(&p1row[tp * 32 + quad * 8]);
    #pragma unroll
    for (int db = 0; db < 4; db++)
      #pragma unroll
      for (int tp = 0; tp < 2; tp++) {
        bf16x8 vf = *reinterpret_cast<const bf16x8*>(
            &Vb[db * 16 + l15][((tp * 4 + quad) ^ x7) << 3]);
        accO[1][db] = __builtin_amdgcn_mfma_f32_16x16x32_bf16(vf, pb1[tp], accO[1][db], 0, 0, 0);
      }
  }

  // epilogue: horizontal lsum, reduce over quads, normalize, write both sides
  #pragma unroll
  for (int f = 0; f < 2; f++) {
    float rs = (lsum[f][0] + lsum[f][1]) + (lsum[f][2] + lsum[f][3]);
    rs += __shfl_xor(rs, 16); rs += __shfl_xor(rs, 32);
    float inv = 1.0f / fmaxf(rs, 1e-30f);
    int srow = (f == 0 ? st0 : st1) * 64 + wave * 16 + l15;
    #pragma unroll
    for (int db = 0; db < 4; db++) {
      ushort4 pk;
      pk.x = f2bf(accO[f][db][0] * inv); pk.y = f2bf(accO[f][db][1] * inv);
      pk.z = f2bf(accO[f][db][2] * inv); pk.w = f2bf(accO[f][db][3] * inv);
      *(ushort4*)&y[((size_t)b * SEQ + srow) * HDIM + h * 64 + db * 16 + quad * 4] = pk;
    }
  }
}

// ---- output projection, 128x64 tile, dbuf issue-early, 1 barrier/step.
// bo dtype-detector moved AFTER the K-loop (only the epilogue needs it):
// removes the 512-elem scan + 2 barriers that serialized block startup.
__global__ __launch_bounds__(256) void out_gemm(
    const unsigned short* __restrict__ y,
    const unsigned short* __restrict__ wot,
    const void* __restrict__ bo,
    float* __restrict__ out) {
  __shared__ __attribute__((aligned(16))) unsigned short Al[2][128 * 64];
  __shared__ __attribute__((aligned(16))) unsigned short Bl[2][64 * 64];
  int tid = threadIdx.x;
  int mt = blockIdx.x, nt = blockIdx.y;
  const unsigned short* A  = y   + (size_t)mt * 128 * HDIM;
  const unsigned short* Bm = wot + (size_t)nt * 64 * HDIM;
  int wave = tid >> 6, lane = tid & 63;
  int quad = lane >> 4, l15 = lane & 15;
  int r8 = lane >> 3, c8 = lane & 7;
  int gcol = ((c8 ^ r8) << 3);
  int x7 = l15 & 7;
  int wm = (wave >> 1) * 64, wn = (wave & 1) * 32;
  f32x4 acc[4][2];
  #pragma unroll
  for (int i = 0; i < 4; i++)
    #pragma unroll
    for (int j = 0; j < 2; j++) acc[i][j] = (f32x4){0.f, 0.f, 0.f, 0.f};

  auto stage = [&](int bb, int k0) {
    #pragma unroll
    for (int c = 0; c < 4; c++) {
      int row = wave * 32 + c * 8 + r8;
      gl_lds16(&A[(size_t)row * HDIM + k0 + gcol], &Al[bb][(wave * 32 + c * 8) * 64]);
    }
    #pragma unroll
    for (int c = 0; c < 2; c++) {
      int row = wave * 16 + c * 8 + r8;
      gl_lds16(&Bm[(size_t)row * HDIM + k0 + gcol], &Bl[bb][(wave * 16 + c * 8) * 64]);
    }
  };

  stage(0, 0);
  __syncthreads();
  for (int ks = 0; ks < 16; ks++) {
    int bb = ks & 1;
    if (ks < 15) stage(bb ^ 1, (ks + 1) * 64);   // issue-early
    #pragma unroll
    for (int h = 0; h < 2; h++) {
      int cq = ((quad + 4 * h) ^ x7) << 3;
      bf16x8 af[4], bfr[2];
      #pragma unroll
      for (int fm = 0; fm < 4; fm++)
        af[fm] = *reinterpret_cast<const bf16x8*>(&Al[bb][(wm + fm * 16 + l15) * 64 + cq]);
      #pragma unroll
      for (int fn = 0; fn < 2; fn++)
        bfr[fn] = *reinterpret_cast<const bf16x8*>(&Bl[bb][(wn + fn * 16 + l15) * 64 + cq]);
      __builtin_amdgcn_s_setprio(1);
      #pragma unroll
      for (int fm = 0; fm < 4; fm++)
        #pragma unroll
        for (int fn = 0; fn < 2; fn++)
          acc[fm][fn] = __builtin_amdgcn_mfma_f32_16x16x32_bf16(af[fm], bfr[fn], acc[fm][fn], 0, 0, 0);
      __builtin_amdgcn_s_setprio(0);
    }
    __syncthreads();
  }

  int fbo = detect_flag_block(bo, 512, tid, 256);   // needed only for bias below

  #pragma unroll
  for (int fn = 0; fn < 2; fn++) {
    int n = nt * 64 + wn + fn * 16 + l15;
    float bias = load_elem(bo, fbo, n);
    #pragma unroll
    for (int fm = 0; fm < 4; fm++) {
      int m = mt * 128 + wm + fm * 16 + quad * 4;
      #pragma unroll
      for (int r = 0; r < 4; r++)
        out[(size_t)(m + r) * CH + n] = acc[fm][fn][r] + bias;
    }
  }
}

extern "C" void kernel_launch(void* const* d_in, const int* in_sizes, int n_in,
                              void* d_out, int out_size, void* d_ws, size_t ws_size,
                              hipStream_t stream) {
  const void* x  = d_in[0];
  const void* Wq = d_in[1];
  const void* Wk = d_in[2];
  const void* Wv = d_in[3];
  const void* Wo = d_in[4];
  const void* bo = d_in[5];
  float* out = (float*)d_out;

  char* ws = (char*)d_ws;
  const size_t MB = 1024 * 1024;
  unsigned short* qb   = (unsigned short*)(ws + 0);        // [B,H,S,D]  8MB (pre-scaled)
  unsigned short* kb   = (unsigned short*)(ws + 8  * MB);  // [B,H,S,D]  8MB
  unsigned short* vtb  = (unsigned short*)(ws + 16 * MB);  // [B,H,D,S]  8MB
  unsigned short* yb   = (unsigned short*)(ws + 24 * MB);  // [B,S,HD]   8MB
  unsigned short* wall = (unsigned short*)(ws + 32 * MB);  // [3][H,D,C] 6MB contiguous
  unsigned short* wot  = (unsigned short*)(ws + 38 * MB);  // [C,HD]     2MB
  unsigned short* xb   = (unsigned short*)(ws + 40 * MB);  // [B,S,C]    8MB bf16

  prep<<<3072, 256, 0, stream>>>(x, Wq, Wk, Wv, Wo, xb, wall, wot);
  qkv_gemm<<<dim3(NB * SEQ / 128, 3 * HDIM / 192), 256, 0, stream>>>(xb, wall, qb, kb, vtb);
  attn_k<<<dim3(16, NB * NH), 256, 0, stream>>>(qb, kb, vtb, yb);
  out_gemm<<<dim3(NB * SEQ / 128, CH / 64), 256, 0, stream>>>(yb, wot, bo, out);
}